// Round 2
// 57.892 us; speedup vs baseline: 1.0928x; 1.0928x over previous
//
#include <hip/hip_runtime.h>

// FractalEmbedding: out[b,l,d] = scale * sum_f feats(token)[f] * W[d,f]
// feats = 8-step Julia iteration on c_table[token], interleaved (zr,zi).
//
// B=8, L=8192 -> 65536 tokens; D=1024; 16 features. Output 268 MB f32.
// Write-BW bound in principle (fill kernel: 7.0 TB/s @ 87% peak), previous
// version measured 4.24 TB/s => latency-bound loop. This version:
//  - dot fused into the Julia recurrence (no f[16] array, shorter chains)
//  - 2 tokens per iteration, recurrences interleaved (2x independent ILP)
//  - next pair's tok/ctab prefetched before current pair's compute
//  - scale folded into register-resident W (scale==1.0 -> exact)
//  - nontemporal float4 stores (output is never re-read); uses a native
//    ext_vector_type since __builtin_nontemporal_store rejects HIP float4

#define STEPS 8
#define NFEAT (2 * STEPS)
#define EMBED 1024
#define NTOK (8 * 8192)
#define NPAIR (NTOK / 2)
#define BLOCK 256
#define GRID 2048

typedef float floatx4 __attribute__((ext_vector_type(4)));

__global__ __launch_bounds__(BLOCK, 4) void FractalEmbedding_30365418782757_kernel(
    const int* __restrict__ tok,
    const float* __restrict__ ctab,   // (V, 2)
    const float* __restrict__ W,      // (1024, 16) row-major
    const float* __restrict__ scale_p,
    float* __restrict__ out)          // (NTOK, 1024)
{
    const int t = threadIdx.x;  // thread t -> output dims 4t .. 4t+3
    const float s = *scale_p;

    // This thread's 4 W rows in registers, scale pre-folded (64 VGPRs).
    float w[4][NFEAT];
#pragma unroll
    for (int r = 0; r < 4; ++r) {
        const float4* wrow = reinterpret_cast<const float4*>(W + (size_t)(4 * t + r) * NFEAT);
#pragma unroll
        for (int q = 0; q < 4; ++q) {
            float4 v = wrow[q];
            w[r][4 * q + 0] = v.x * s;
            w[r][4 * q + 1] = v.y * s;
            w[r][4 * q + 2] = v.z * s;
            w[r][4 * q + 3] = v.w * s;
        }
    }

    const int2*   tok2  = reinterpret_cast<const int2*>(tok);
    const float2* ctab2 = reinterpret_cast<const float2*>(ctab);

    // Prologue: load first pair's ids + constants (wave-uniform scalar loads).
    int p = blockIdx.x;
    int2   id = tok2[p];
    float2 c0 = ctab2[id.x];
    float2 c1 = ctab2[id.y];

    for (; p < NPAIR; p += GRID) {
        // Prefetch next pair (clamped so the load is always in-bounds);
        // overlaps the dependent tok->ctab chain with this pair's compute.
        const int pn = p + GRID;
        const int pc = (pn < NPAIR) ? pn : p;
        int2   idn = tok2[pc];
        float2 cn0 = ctab2[idn.x];
        float2 cn1 = ctab2[idn.y];

        // Two interleaved Julia recurrences with the dot fused per step.
        // Accumulation order per output dim is identical to the reference
        // loop (f0*w0, f1*w1, ... sequentially).
        float acc0[4] = {0.f, 0.f, 0.f, 0.f};
        float acc1[4] = {0.f, 0.f, 0.f, 0.f};
        float zr0 = 0.f, zi0 = 0.f, zr1 = 0.f, zi1 = 0.f;
#pragma unroll
        for (int st = 0; st < STEPS; ++st) {
            float a0 = zr0 * zr0 - zi0 * zi0 + c0.x;
            float b0 = 2.0f * zr0 * zi0 + c0.y;
            zr0 = a0; zi0 = b0;
            float a1 = zr1 * zr1 - zi1 * zi1 + c1.x;
            float b1 = 2.0f * zr1 * zi1 + c1.y;
            zr1 = a1; zi1 = b1;
#pragma unroll
            for (int r = 0; r < 4; ++r) {
                acc0[r] += zr0 * w[r][2 * st];
                acc0[r] += zi0 * w[r][2 * st + 1];
                acc1[r] += zr1 * w[r][2 * st];
                acc1[r] += zi1 * w[r][2 * st + 1];
            }
        }

        floatx4 o0 = {acc0[0], acc0[1], acc0[2], acc0[3]};
        floatx4 o1 = {acc1[0], acc1[1], acc1[2], acc1[3]};
        __builtin_nontemporal_store(o0, reinterpret_cast<floatx4*>(out + (size_t)(2 * p)     * EMBED) + t);
        __builtin_nontemporal_store(o1, reinterpret_cast<floatx4*>(out + (size_t)(2 * p + 1) * EMBED) + t);

        c0 = cn0;
        c1 = cn1;
    }
}

extern "C" void kernel_launch(void* const* d_in, const int* in_sizes, int n_in,
                              void* d_out, int out_size, void* d_ws, size_t ws_size,
                              hipStream_t stream) {
    const int*   tok   = (const int*)d_in[0];
    const float* ctab  = (const float*)d_in[1];
    const float* W     = (const float*)d_in[2];
    const float* scale = (const float*)d_in[3];
    float*       out   = (float*)d_out;

    FractalEmbedding_30365418782757_kernel<<<GRID, BLOCK, 0, stream>>>(tok, ctab, W, scale, out);
}